// Round 2
// baseline (263.759 us; speedup 1.0000x reference)
//
#include <hip/hip_runtime.h>
#include <hip/hip_bf16.h>

typedef unsigned short u16;
typedef unsigned int u32;
typedef __bf16 bf16x8 __attribute__((ext_vector_type(8)));
typedef float f32x4 __attribute__((ext_vector_type(4)));

#define NB 2
#define NSEQ 2048
#define NDIM 1024
#define NH 16
#define NDH 64

static __device__ __forceinline__ u16 f2bf(float f) {
  union { float f; u32 u; } a; a.f = f;
  u32 u = a.u;
  return (u16)((u + 0x7fffu + ((u >> 16) & 1u)) >> 16);  // RNE, no NaNs in data
}
static __device__ __forceinline__ float bf2f(u16 u) {
  union { u32 u; float f; } a; a.u = ((u32)u) << 16; return a.f;
}
static __device__ __forceinline__ bf16x8 ldbf8(const u16* p) {
  return *(const bf16x8*)p;
}
static __device__ __forceinline__ f32x4 mfma16(bf16x8 a, bf16x8 b, f32x4 c) {
  return __builtin_amdgcn_mfma_f32_16x16x32_bf16(a, b, c, 0, 0, 0);
}

// ---------- transpose + fp32 -> bf16 : out[c][r] = bf16(in[r][c]) ----------
__global__ __launch_bounds__(256) void k_transpose(const float* __restrict__ in,
                                                   u16* __restrict__ out,
                                                   int R, int C) {
  __shared__ u16 tile[64][65];
  const int r0 = blockIdx.x * 64, c0 = blockIdx.y * 64;
  const int t = threadIdx.x;
  const int tr = t >> 6;      // 0..3
  const int tc = t & 63;
#pragma unroll 4
  for (int p = 0; p < 16; p++) {
    int r = p * 4 + tr;
    tile[r][tc] = f2bf(in[(size_t)(r0 + r) * C + (c0 + tc)]);
  }
  __syncthreads();
#pragma unroll 4
  for (int p = 0; p < 16; p++) {
    int rr = p * 4 + tr;
    out[(size_t)(c0 + rr) * R + (r0 + tc)] = tile[tc][rr];
  }
}

// ---------- RMSNorm (l2norm * sqrt(DIM) * (gamma+1)), fp32 -> bf16 ----------
__global__ __launch_bounds__(256) void k_rmsnorm(const float* __restrict__ x,
                                                 const float* __restrict__ gamma,
                                                 u16* __restrict__ xn) {
  __shared__ float part[4];
  const int row = blockIdx.x;
  const int t = threadIdx.x;
  const float4 v = ((const float4*)(x + (size_t)row * NDIM))[t];
  float ss = v.x * v.x + v.y * v.y + v.z * v.z + v.w * v.w;
#pragma unroll
  for (int off = 1; off < 64; off <<= 1) ss += __shfl_xor(ss, off, 64);
  if ((t & 63) == 0) part[t >> 6] = ss;
  __syncthreads();
  const float tot = part[0] + part[1] + part[2] + part[3];
  const float scale = 32.0f / fmaxf(sqrtf(tot), 1e-12f);  // sqrt(1024)=32
  const float4 g = ((const float4*)gamma)[t];
  u16 o0 = f2bf(v.x * scale * (g.x + 1.0f));
  u16 o1 = f2bf(v.y * scale * (g.y + 1.0f));
  u16 o2 = f2bf(v.z * scale * (g.z + 1.0f));
  u16 o3 = f2bf(v.w * scale * (g.w + 1.0f));
  uint2 pv;
  pv.x = (u32)o0 | ((u32)o1 << 16);
  pv.y = (u32)o2 | ((u32)o3 << 16);
  *(uint2*)(xn + (size_t)row * NDIM + t * 4) = pv;
}

// ---------- GEMM: C[M,N] = A[M,1024] @ BT[N,1024]^T (bf16 in) --------------
// EPI 0: write fp32 Of[row*1024 + col]  (final out-proj, straight to d_out)
// EPI 1: scatter bf16 into q/k/v buffers laid out [B,H,N,DH]
template <int EPI>
__global__ __launch_bounds__(256) void k_gemm_bt(const u16* __restrict__ A,
                                                 const u16* __restrict__ BT,
                                                 float* __restrict__ Of,
                                                 u16* __restrict__ O0,
                                                 u16* __restrict__ O1,
                                                 u16* __restrict__ O2) {
  constexpr int KD = 1024;
  __shared__ u16 As[128][40];
  __shared__ u16 Bs[128][40];
  const int m0 = blockIdx.x * 128, n0 = blockIdx.y * 128;
  const int t = threadIdx.x;
  const int w = t >> 6, l = t & 63, lo = l & 15, hi = l >> 4;
  const int wr = (w >> 1) * 64, wc = (w & 1) * 64;
  const int ar = t >> 1, ac = (t & 1) * 16;
  f32x4 acc[4][4] = {};
  const u16* ag = A + (size_t)(m0 + ar) * KD + ac;
  const u16* bg = BT + (size_t)(n0 + ar) * KD + ac;
  for (int k0 = 0; k0 < KD; k0 += 32) {
    uint4 av0 = *(const uint4*)(ag + k0);
    uint4 av1 = *(const uint4*)(ag + k0 + 8);
    uint4 bv0 = *(const uint4*)(bg + k0);
    uint4 bv1 = *(const uint4*)(bg + k0 + 8);
    __syncthreads();
    *(uint4*)&As[ar][ac] = av0; *(uint4*)&As[ar][ac + 8] = av1;
    *(uint4*)&Bs[ar][ac] = bv0; *(uint4*)&Bs[ar][ac + 8] = bv1;
    __syncthreads();
    bf16x8 af[4], bb[4];
#pragma unroll
    for (int i = 0; i < 4; i++) af[i] = ldbf8(&As[wr + i * 16 + lo][hi * 8]);
#pragma unroll
    for (int i = 0; i < 4; i++) bb[i] = ldbf8(&Bs[wc + i * 16 + lo][hi * 8]);
#pragma unroll
    for (int i = 0; i < 4; i++)
#pragma unroll
      for (int j = 0; j < 4; j++)
        acc[i][j] = mfma16(af[i], bb[j], acc[i][j]);
  }
#pragma unroll
  for (int i = 0; i < 4; i++) {
#pragma unroll
    for (int j = 0; j < 4; j++) {
      const int gr0 = m0 + wr + i * 16 + hi * 4;
      const int gc = n0 + wc + j * 16 + lo;
#pragma unroll
      for (int r = 0; r < 4; r++) {
        const int row = gr0 + r;
        if (EPI == 0) {
          Of[(size_t)row * 1024 + gc] = acc[i][j][r];   // fp32 output!
        } else {
          const u16 bv = f2bf(acc[i][j][r]);
          const int which = gc >> 10, rem = gc & 1023;
          const int h = rem >> 6, dh = rem & 63;
          const int b = row >> 11, ns = row & 2047;
          const size_t idx = ((((size_t)b * NH + h) * NSEQ) + ns) * NDH + dh;
          (which == 0 ? O0 : which == 1 ? O1 : O2)[idx] = bv;
        }
      }
    }
  }
}

// ---------- rotary (interleaved pairs) + optional scale, in place ----------
__global__ __launch_bounds__(256) void k_rotary(u16* __restrict__ qk,
                                                const float* __restrict__ rot,
                                                float scale) {
  const int i = blockIdx.x * 256 + threadIdx.x;  // 8-element group
  const int d0 = (i & 7) * 8;
  const int n = (i >> 3) & (NSEQ - 1);
  union { uint4 v; u16 s[8]; } u;
  u.v = *(const uint4*)(qk + (size_t)i * 8);
  float fr[8];
  *(float4*)&fr[0] = *(const float4*)(rot + n * NDH + d0);
  *(float4*)&fr[4] = *(const float4*)(rot + n * NDH + d0 + 4);
  union { uint4 v; u16 s[8]; } o;
#pragma unroll
  for (int p = 0; p < 4; p++) {
    float a = bf2f(u.s[2 * p]), b = bf2f(u.s[2 * p + 1]);
    float s0, c0, s1, c1;
    __sincosf(fr[2 * p], &s0, &c0);
    __sincosf(fr[2 * p + 1], &s1, &c1);
    o.s[2 * p] = f2bf((a * c0 - b * s0) * scale);
    o.s[2 * p + 1] = f2bf((b * c1 + a * s1) * scale);
  }
  *(uint4*)(qk + (size_t)i * 8) = o.v;
}

// ---------- flash attention: softcap + causal + online softmax -------------
__global__ __launch_bounds__(256) void k_attn(const u16* __restrict__ Q,
                                              const u16* __restrict__ K,
                                              const u16* __restrict__ V,
                                              u16* __restrict__ O) {
  __shared__ u16 Ks[64][72];        // [kv][dh], padded (conflict-free b128)
  __shared__ u16 Vs[64][64];        // [dh][kv], XOR-swizzled kv blocks
  __shared__ u16 Ps[4][16][72];     // per-wave P tile [qrow][kv]
  const int bh = blockIdx.x >> 5;
  const int qt = 31 - (blockIdx.x & 31);   // heavy tiles first
  const int b = bh >> 4, h = bh & 15;
  const size_t base = (size_t)bh * (NSEQ * NDH);
  const int t = threadIdx.x;
  const int w = t >> 6, l = t & 63, lo = l & 15, hi = l >> 4;
  const int q0 = qt * 64;

  bf16x8 aq0, aq1;
  {
    const u16* qp = Q + base + (size_t)(q0 + w * 16 + lo) * NDH;
    aq0 = ldbf8(qp + hi * 8);
    aq1 = ldbf8(qp + 32 + hi * 8);
  }
  f32x4 accO[4] = {};
  float m_run[4], l_run[4];
#pragma unroll
  for (int r = 0; r < 4; r++) { m_run[r] = -1e30f; l_run[r] = 0.0f; }

  const int vkv = t >> 3;        // 0..31
  const int vd0 = (t & 7) * 8;

  for (int kt = 0; kt <= qt; kt++) {
    __syncthreads();
    {  // stage K tile [64][64]
      const int r = t >> 2, c = (t & 3) * 16;
      const u16* kp = K + base + (size_t)(kt * 64 + r) * NDH + c;
      *(uint4*)&Ks[r][c] = *(const uint4*)kp;
      *(uint4*)&Ks[r][c + 8] = *(const uint4*)(kp + 8);
    }
#pragma unroll
    for (int p = 0; p < 2; p++) {  // stage V transposed, swizzled
      const int kv = p * 32 + vkv;
      union { uint4 q; u16 s[8]; } u;
      u.q = *(const uint4*)(V + base + (size_t)(kt * 64 + kv) * NDH + vd0);
      const int kl = kv & 7, kh = kv >> 3;
#pragma unroll
      for (int i = 0; i < 8; i++) {
        const int d = vd0 + i;
        const int fd = (d & 7) ^ ((d >> 3) & 7);
        Vs[d][kl + 8 * (kh ^ fd)] = u.s[i];
      }
    }
    __syncthreads();

    // S = Q K^T  (rows: q, cols: kv)
    f32x4 s[4];
#pragma unroll
    for (int nt = 0; nt < 4; nt++) {
      f32x4 z = {};
      z = mfma16(aq0, ldbf8(&Ks[nt * 16 + lo][hi * 8]), z);
      z = mfma16(aq1, ldbf8(&Ks[nt * 16 + lo][32 + hi * 8]), z);
      s[nt] = z;
    }
    // softcap + causal mask
    const bool diag = (kt == qt);
    const int rowg = q0 + w * 16 + hi * 4;
#pragma unroll
    for (int nt = 0; nt < 4; nt++) {
      const int col = kt * 64 + nt * 16 + lo;
#pragma unroll
      for (int r = 0; r < 4; r++) {
        float v = s[nt][r];
        const float a = fabsf(v) * 0.02f;           // |v|/SOFTCAP
        const float e = __expf(-2.0f * a);
        const float th = (1.0f - e) / (1.0f + e);
        v = copysignf(th * 50.0f, v);
        if (diag && col > rowg + r) v = -1e30f;
        s[nt][r] = v;
      }
    }
    // online softmax (row stats across the 16 lanes of each hi-group)
    float corr[4];
#pragma unroll
    for (int r = 0; r < 4; r++) {
      float mx = fmaxf(fmaxf(s[0][r], s[1][r]), fmaxf(s[2][r], s[3][r]));
      mx = fmaxf(mx, __shfl_xor(mx, 1, 64));
      mx = fmaxf(mx, __shfl_xor(mx, 2, 64));
      mx = fmaxf(mx, __shfl_xor(mx, 4, 64));
      mx = fmaxf(mx, __shfl_xor(mx, 8, 64));
      const float mn = fmaxf(m_run[r], mx);
      corr[r] = __expf(m_run[r] - mn);   // first tile: exp(-huge) = 0
      m_run[r] = mn;
    }
    float rs[4] = {0.f, 0.f, 0.f, 0.f};
#pragma unroll
    for (int nt = 0; nt < 4; nt++)
#pragma unroll
      for (int r = 0; r < 4; r++) {
        const float p = __expf(s[nt][r] - m_run[r]);
        s[nt][r] = p;
        rs[r] += p;
      }
#pragma unroll
    for (int r = 0; r < 4; r++) {
      rs[r] += __shfl_xor(rs[r], 1, 64);
      rs[r] += __shfl_xor(rs[r], 2, 64);
      rs[r] += __shfl_xor(rs[r], 4, 64);
      rs[r] += __shfl_xor(rs[r], 8, 64);
      l_run[r] = l_run[r] * corr[r] + rs[r];
    }
#pragma unroll
    for (int dt = 0; dt < 4; dt++)
#pragma unroll
      for (int r = 0; r < 4; r++) accO[dt][r] *= corr[r];

    // P -> LDS (bf16, verified C layout -> plain [qrow][kv] array)
#pragma unroll
    for (int nt = 0; nt < 4; nt++)
#pragma unroll
      for (int r = 0; r < 4; r++)
        Ps[w][hi * 4 + r][nt * 16 + lo] = f2bf(s[nt][r]);
    asm volatile("s_waitcnt lgkmcnt(0)" ::: "memory");  // wave-local wr->rd

    const bf16x8 ap0 = ldbf8(&Ps[w][lo][hi * 8]);
    const bf16x8 ap1 = ldbf8(&Ps[w][lo][32 + hi * 8]);
#pragma unroll
    for (int dt = 0; dt < 4; dt++) {
      const int d = dt * 16 + lo;
      const int fd = (d & 7) ^ ((d >> 3) & 7);
      const bf16x8 bv0 = ldbf8(&Vs[d][8 * (hi ^ fd)]);
      const bf16x8 bv1 = ldbf8(&Vs[d][8 * ((4 + hi) ^ fd)]);
      accO[dt] = mfma16(ap0, bv0, accO[dt]);
      accO[dt] = mfma16(ap1, bv1, accO[dt]);
    }
  }
  // epilogue: normalize, write O as [B,N,H,DH]
#pragma unroll
  for (int dt = 0; dt < 4; dt++) {
#pragma unroll
    for (int r = 0; r < 4; r++) {
      const int row = q0 + w * 16 + hi * 4 + r;
      const float v = accO[dt][r] / l_run[r];
      const size_t idx = (((size_t)(b * NSEQ + row)) * NH + h) * NDH + dt * 16 + lo;
      O[idx] = f2bf(v);
    }
  }
}

extern "C" void kernel_launch(void* const* d_in, const int* in_sizes, int n_in,
                              void* d_out, int out_size, void* d_ws, size_t ws_size,
                              hipStream_t stream) {
  const float* x     = (const float*)d_in[0];
  // d_in[1] = attn_mask (bool causal tril) -- implemented directly
  const float* rot   = (const float*)d_in[2];
  const float* gamma = (const float*)d_in[3];
  const float* wqkv  = (const float*)d_in[4];
  const float* wout  = (const float*)d_in[5];

  char* ws = (char*)d_ws;
  u16* xn    = (u16*)(ws);                        // 8 MB, reused as attn-out
  u16* wqkvT = (u16*)(ws + (size_t)( 8u << 20));  // 6 MB
  u16* woutT = (u16*)(ws + (size_t)(14u << 20));  // 2 MB
  u16* qb    = (u16*)(ws + (size_t)(16u << 20));  // 8 MB
  u16* kb    = (u16*)(ws + (size_t)(24u << 20));  // 8 MB
  u16* vb    = (u16*)(ws + (size_t)(32u << 20));  // 8 MB
  u16* ob    = xn;                                 // xn dead after QKV GEMM

  k_transpose<<<dim3(16, 48), 256, 0, stream>>>(wqkv, wqkvT, 1024, 3072);
  k_transpose<<<dim3(16, 16), 256, 0, stream>>>(wout, woutT, 1024, 1024);
  k_rmsnorm<<<4096, 256, 0, stream>>>(x, gamma, xn);
  k_gemm_bt<1><<<dim3(32, 24), 256, 0, stream>>>(xn, wqkvT, nullptr, qb, kb, vb);
  k_rotary<<<2048, 256, 0, stream>>>(qb, rot, 0.125f);  // q * DH^-0.5 folded in
  k_rotary<<<2048, 256, 0, stream>>>(kb, rot, 1.0f);
  k_attn<<<1024, 256, 0, stream>>>(qb, kb, vb, ob);
  k_gemm_bt<0><<<dim3(32, 8), 256, 0, stream>>>(ob, woutT, (float*)d_out, nullptr, nullptr, nullptr);
}

// Round 4
// 170.192 us; speedup vs baseline: 1.5498x; 1.5498x over previous
//
#include <hip/hip_runtime.h>
#include <hip/hip_bf16.h>

typedef unsigned short u16;
typedef unsigned int u32;
typedef __bf16 bf16x8 __attribute__((ext_vector_type(8)));
typedef float f32x4 __attribute__((ext_vector_type(4)));

#define NB 2
#define NSEQ 2048
#define NDIM 1024
#define NH 16
#define NDH 64

static __device__ __forceinline__ u16 f2bf(float f) {
  return __builtin_bit_cast(u16, (__bf16)f);   // hw v_cvt RNE
}
static __device__ __forceinline__ float bf2f(u16 u) {
  union { u32 u; float f; } a; a.u = ((u32)u) << 16; return a.f;
}
static __device__ __forceinline__ bf16x8 ldbf8(const u16* p) {
  return *(const bf16x8*)p;
}
static __device__ __forceinline__ f32x4 mfma16(bf16x8 a, bf16x8 b, f32x4 c) {
  return __builtin_amdgcn_mfma_f32_16x16x32_bf16(a, b, c, 0, 0, 0);
}
static __device__ __forceinline__ float fexp2(float x) {
  return __builtin_amdgcn_exp2f(x);            // v_exp_f32: 2^x
}

// ---------- transpose + fp32 -> bf16 : out[c][r] = bf16(in[r][c]) ----------
__global__ __launch_bounds__(256) void k_transpose(const float* __restrict__ in,
                                                   u16* __restrict__ out,
                                                   int R, int C) {
  __shared__ u16 tile[64][65];
  const int r0 = blockIdx.x * 64, c0 = blockIdx.y * 64;
  const int t = threadIdx.x;
  const int tr = t >> 6;      // 0..3
  const int tc = t & 63;
#pragma unroll 4
  for (int p = 0; p < 16; p++) {
    int r = p * 4 + tr;
    tile[r][tc] = f2bf(in[(size_t)(r0 + r) * C + (c0 + tc)]);
  }
  __syncthreads();
#pragma unroll 4
  for (int p = 0; p < 16; p++) {
    int rr = p * 4 + tr;
    out[(size_t)(c0 + rr) * R + (r0 + tc)] = tile[tc][rr];
  }
}

// ---------- RMSNorm (l2norm * sqrt(DIM) * (gamma+1)), fp32 -> bf16 ----------
__global__ __launch_bounds__(256) void k_rmsnorm(const float* __restrict__ x,
                                                 const float* __restrict__ gamma,
                                                 u16* __restrict__ xn) {
  __shared__ float part[4];
  const int row = blockIdx.x;
  const int t = threadIdx.x;
  const float4 v = ((const float4*)(x + (size_t)row * NDIM))[t];
  float ss = v.x * v.x + v.y * v.y + v.z * v.z + v.w * v.w;
#pragma unroll
  for (int off = 1; off < 64; off <<= 1) ss += __shfl_xor(ss, off, 64);
  if ((t & 63) == 0) part[t >> 6] = ss;
  __syncthreads();
  const float tot = part[0] + part[1] + part[2] + part[3];
  const float scale = 32.0f / fmaxf(sqrtf(tot), 1e-12f);  // sqrt(1024)=32
  const float4 g = ((const float4*)gamma)[t];
  u16 o0 = f2bf(v.x * scale * (g.x + 1.0f));
  u16 o1 = f2bf(v.y * scale * (g.y + 1.0f));
  u16 o2 = f2bf(v.z * scale * (g.z + 1.0f));
  u16 o3 = f2bf(v.w * scale * (g.w + 1.0f));
  uint2 pv;
  pv.x = (u32)o0 | ((u32)o1 << 16);
  pv.y = (u32)o2 | ((u32)o3 << 16);
  *(uint2*)(xn + (size_t)row * NDIM + t * 4) = pv;
}

// ---------- GEMM: C[M,N] = A[M,1024] @ BT[N,1024]^T (bf16 in) --------------
// EPI 0: write fp32 Of[row*1024 + col]  (final out-proj, straight to d_out)
// EPI 1: scatter bf16 -> Q,K as [B,H,N,DH]; V TRANSPOSED as [B,H,DH,NSEQ]
template <int EPI>
__global__ __launch_bounds__(256) void k_gemm_bt(const u16* __restrict__ A,
                                                 const u16* __restrict__ BT,
                                                 float* __restrict__ Of,
                                                 u16* __restrict__ O0,
                                                 u16* __restrict__ O1,
                                                 u16* __restrict__ O2) {
  constexpr int KD = 1024;
  __shared__ u16 As[128][40];
  __shared__ u16 Bs[128][40];
  const int m0 = blockIdx.x * 128, n0 = blockIdx.y * 128;
  const int t = threadIdx.x;
  const int w = t >> 6, l = t & 63, lo = l & 15, hi = l >> 4;
  const int wr = (w >> 1) * 64, wc = (w & 1) * 64;
  const int ar = t >> 1, ac = (t & 1) * 16;
  f32x4 acc[4][4] = {};
  const u16* ag = A + (size_t)(m0 + ar) * KD + ac;
  const u16* bg = BT + (size_t)(n0 + ar) * KD + ac;
  for (int k0 = 0; k0 < KD; k0 += 32) {
    uint4 av0 = *(const uint4*)(ag + k0);
    uint4 av1 = *(const uint4*)(ag + k0 + 8);
    uint4 bv0 = *(const uint4*)(bg + k0);
    uint4 bv1 = *(const uint4*)(bg + k0 + 8);
    __syncthreads();
    *(uint4*)&As[ar][ac] = av0; *(uint4*)&As[ar][ac + 8] = av1;
    *(uint4*)&Bs[ar][ac] = bv0; *(uint4*)&Bs[ar][ac + 8] = bv1;
    __syncthreads();
    bf16x8 af[4], bb[4];
#pragma unroll
    for (int i = 0; i < 4; i++) af[i] = ldbf8(&As[wr + i * 16 + lo][hi * 8]);
#pragma unroll
    for (int i = 0; i < 4; i++) bb[i] = ldbf8(&Bs[wc + i * 16 + lo][hi * 8]);
#pragma unroll
    for (int i = 0; i < 4; i++)
#pragma unroll
      for (int j = 0; j < 4; j++)
        acc[i][j] = mfma16(af[i], bb[j], acc[i][j]);
  }
#pragma unroll
  for (int i = 0; i < 4; i++) {
#pragma unroll
    for (int j = 0; j < 4; j++) {
      const int gr0 = m0 + wr + i * 16 + hi * 4;
      const int gc = n0 + wc + j * 16 + lo;
#pragma unroll
      for (int r = 0; r < 4; r++) {
        const int row = gr0 + r;
        if (EPI == 0) {
          Of[(size_t)row * 1024 + gc] = acc[i][j][r];   // fp32 output
        } else {
          const u16 bv = f2bf(acc[i][j][r]);
          const int which = gc >> 10, rem = gc & 1023;
          const int h = rem >> 6, dh = rem & 63;
          const int b = row >> 11, ns = row & 2047;
          if (which == 2) {   // V transposed: [B,H,DH,NSEQ]
            O2[(((size_t)b * NH + h) * NDH + dh) * NSEQ + ns] = bv;
          } else {
            const size_t idx = ((((size_t)b * NH + h) * NSEQ) + ns) * NDH + dh;
            (which == 0 ? O0 : O1)[idx] = bv;
          }
        }
      }
    }
  }
}

// ---------- rotary (interleaved pairs) on q (scaled) and k, fused ----------
__global__ __launch_bounds__(256) void k_rotary(u16* __restrict__ qb,
                                                u16* __restrict__ kb,
                                                const float* __restrict__ rot) {
  const int gi = blockIdx.x * 256 + threadIdx.x;   // 8-elem group id
  const int half = gi >> 19;                       // 2^19 groups per tensor
  const int i = gi & ((1 << 19) - 1);
  u16* buf = half ? kb : qb;
  const float scale = half ? 1.0f : 0.125f;        // q * DH^-0.5 folded in
  const int d0 = (i & 7) * 8;
  const int n = (i >> 3) & (NSEQ - 1);
  union { uint4 v; u16 s[8]; } u;
  u.v = *(const uint4*)(buf + (size_t)i * 8);
  float fr[8];
  *(float4*)&fr[0] = *(const float4*)(rot + n * NDH + d0);
  *(float4*)&fr[4] = *(const float4*)(rot + n * NDH + d0 + 4);
  union { uint4 v; u16 s[8]; } o;
#pragma unroll
  for (int p = 0; p < 4; p++) {
    float a = bf2f(u.s[2 * p]), b = bf2f(u.s[2 * p + 1]);
    float s0, c0, s1, c1;
    __sincosf(fr[2 * p], &s0, &c0);
    __sincosf(fr[2 * p + 1], &s1, &c1);
    o.s[2 * p] = f2bf((a * c0 - b * s0) * scale);
    o.s[2 * p + 1] = f2bf((b * c1 + a * s1) * scale);
  }
  *(uint4*)(buf + (size_t)i * 8) = o.v;
}

// ---------- flash attention: softcap, fixed-m softmax (m=0), causal --------
// p = exp(50*tanh(s/50)) in [2^-73, 2^73]: no overflow/underflow, no running
// max, no rescale, no per-tile cross-lane reductions. l reduced at epilogue.
#define KCH(row, ch) ((((ch) ^ ((row) & 7)) * 8))
__global__ __launch_bounds__(128) void k_attn(const u16* __restrict__ Q,
                                              const u16* __restrict__ K,
                                              const u16* __restrict__ Vt,
                                              u16* __restrict__ O) {
  __shared__ u16 Ks[64][64];        // [kv][dh], 16B-chunk XOR swizzled
  __shared__ u16 Vs[64][64];        // [dh][kv], 16B-chunk XOR swizzled
  __shared__ u16 Ps[2][16][76];     // per-wave P [qrow][kv], stride 76
  const int qt = 63 - (blockIdx.x >> 5);   // global heavy-first
  const int bh = blockIdx.x & 31;
  const int b = bh >> 4, h = bh & 15;
  const size_t base = (size_t)bh * (NSEQ * NDH);
  const int t = threadIdx.x;
  const int w = t >> 6, l = t & 63, lo = l & 15, hi = l >> 4;
  const int q0 = qt * 32;

  bf16x8 aq0, aq1;
  {
    const u16* qp = Q + base + (size_t)(q0 + w * 16 + lo) * NDH;
    aq0 = ldbf8(qp + hi * 8);
    aq1 = ldbf8(qp + 32 + hi * 8);
  }
  f32x4 accO[4] = {};
  float l_part[4] = {0.f, 0.f, 0.f, 0.f};

  const int sr = t >> 1;                 // staging row 0..63
  const int sh = (t & 1) * 4;            // staging chunk-half base (0 or 4)
  const u16* kg = K + base + (size_t)sr * NDH;
  const u16* vg = Vt + ((size_t)bh * NDH + sr) * NSEQ;
  const int nkt = (qt >> 1) + 1;
  const int ktd = qt >> 1;               // diagonal tile index
  const int rowg = q0 + w * 16 + hi * 4;

  for (int kt = 0; kt < nkt; kt++) {
    __syncthreads();
    {
      const u16* kp = kg + (size_t)kt * 64 * NDH;
      const u16* vp = vg + kt * 64;
#pragma unroll
      for (int j = 0; j < 4; j++) {
        const int c = sh + j;
        *(uint4*)&Ks[sr][KCH(sr, c)] = *(const uint4*)(kp + c * 8);
        *(uint4*)&Vs[sr][KCH(sr, c)] = *(const uint4*)(vp + c * 8);
      }
    }
    __syncthreads();

    // S = Q K^T
    f32x4 s[4];
#pragma unroll
    for (int nt = 0; nt < 4; nt++) {
      const int kr = nt * 16 + lo;
      f32x4 z = {};
      z = mfma16(aq0, ldbf8(&Ks[kr][KCH(kr, hi)]), z);
      z = mfma16(aq1, ldbf8(&Ks[kr][KCH(kr, 4 + hi)]), z);
      s[nt] = z;
    }
    // softcap + exp (fixed m = 0) + causal mask
    const bool diag = (kt == ktd);
#pragma unroll
    for (int nt = 0; nt < 4; nt++) {
      const int col = kt * 64 + nt * 16 + lo;
#pragma unroll
      for (int r = 0; r < 4; r++) {
        const float v = s[nt][r];
        const float e = fexp2(fabsf(v) * -0.0577078016f);    // 2/(50 ln2)
        const float tt = (1.0f - e) * __builtin_amdgcn_rcpf(1.0f + e);
        const float sc = copysignf(tt * 72.1347520444f, v);  // 50*log2(e)
        float p = fexp2(sc);
        if (diag && col > rowg + r) p = 0.0f;
        s[nt][r] = p;
        l_part[r] += p;
      }
    }
    // P -> LDS (bf16), transpose C-layout -> A-frag layout
#pragma unroll
    for (int nt = 0; nt < 4; nt++)
#pragma unroll
      for (int r = 0; r < 4; r++)
        Ps[w][hi * 4 + r][nt * 16 + lo] = f2bf(s[nt][r]);

    const bf16x8 ap0 = ldbf8(&Ps[w][lo][hi * 8]);
    const bf16x8 ap1 = ldbf8(&Ps[w][lo][32 + hi * 8]);
#pragma unroll
    for (int dt = 0; dt < 4; dt++) {
      const int d = dt * 16 + lo;
      accO[dt] = mfma16(ap0, ldbf8(&Vs[d][KCH(d, hi)]), accO[dt]);
      accO[dt] = mfma16(ap1, ldbf8(&Vs[d][KCH(d, 4 + hi)]), accO[dt]);
    }
  }
  // epilogue: reduce l across the 16 lo-lanes, normalize, write [B,N,H*DH]
  float lr[4];
#pragma unroll
  for (int r = 0; r < 4; r++) {
    float lv = l_part[r];
    lv += __shfl_xor(lv, 1, 64);
    lv += __shfl_xor(lv, 2, 64);
    lv += __shfl_xor(lv, 4, 64);
    lv += __shfl_xor(lv, 8, 64);
    lr[r] = __builtin_amdgcn_rcpf(lv);
  }
#pragma unroll
  for (int dt = 0; dt < 4; dt++) {
#pragma unroll
    for (int r = 0; r < 4; r++) {
      const int row = rowg + r;
      const float v = accO[dt][r] * lr[r];
      const size_t idx = (((size_t)(b * NSEQ + row)) * NH + h) * NDH + dt * 16 + lo;
      O[idx] = f2bf(v);
    }
  }
}

extern "C" void kernel_launch(void* const* d_in, const int* in_sizes, int n_in,
                              void* d_out, int out_size, void* d_ws, size_t ws_size,
                              hipStream_t stream) {
  const float* x     = (const float*)d_in[0];
  // d_in[1] = attn_mask (bool causal tril) -- implemented directly
  const float* rot   = (const float*)d_in[2];
  const float* gamma = (const float*)d_in[3];
  const float* wqkv  = (const float*)d_in[4];
  const float* wout  = (const float*)d_in[5];

  char* ws = (char*)d_ws;
  u16* xn    = (u16*)(ws);                        // 8 MB, reused as attn-out
  u16* wqkvT = (u16*)(ws + (size_t)( 8u << 20));  // 6 MB
  u16* woutT = (u16*)(ws + (size_t)(14u << 20));  // 2 MB
  u16* qb    = (u16*)(ws + (size_t)(16u << 20));  // 8 MB
  u16* kb    = (u16*)(ws + (size_t)(24u << 20));  // 8 MB
  u16* vt    = (u16*)(ws + (size_t)(32u << 20));  // 8 MB  [B,H,DH,NSEQ]
  u16* ob    = xn;                                 // xn dead after QKV GEMM

  k_transpose<<<dim3(16, 48), 256, 0, stream>>>(wqkv, wqkvT, 1024, 3072);
  k_transpose<<<dim3(16, 16), 256, 0, stream>>>(wout, woutT, 1024, 1024);
  k_rmsnorm<<<4096, 256, 0, stream>>>(x, gamma, xn);
  k_gemm_bt<1><<<dim3(32, 24), 256, 0, stream>>>(xn, wqkvT, nullptr, qb, kb, vt);
  k_rotary<<<4096, 256, 0, stream>>>(qb, kb, rot);
  k_attn<<<2048, 128, 0, stream>>>(qb, kb, vt, ob);
  k_gemm_bt<0><<<dim3(32, 8), 256, 0, stream>>>(ob, woutT, (float*)d_out, nullptr, nullptr, nullptr);
}